// Round 8
// baseline (2334.503 us; speedup 1.0000x reference)
//
#include <hip/hip_runtime.h>
#include <hip/hip_bf16.h>

#define BB   128
#define SS   256
#define DD   512
#define HH   1024
#define NCC  128
#define NCLS 129
#define G4   4096   // 4*HH, gate-interleaved: j = hcol*4 + gate (f,i,g,o)
#define NWG  128    // persistent grid (4-wave WGs); <= half of 256 CUs even at 1 WG/CU

typedef __attribute__((ext_vector_type(8))) short  short8;
typedef __attribute__((ext_vector_type(4))) float  f32x4;

static __device__ __forceinline__ float sigm(float x)  { return 1.0f / (1.0f + __expf(-x)); }
static __device__ __forceinline__ float tanh_(float x) { return 1.0f - 2.0f / (__expf(2.0f * x) + 1.0f); }
static __device__ __forceinline__ unsigned short f2b(float v) {
    __hip_bfloat16 h = __float2bfloat16(v);
    return *reinterpret_cast<unsigned short*>(&h);
}
static __device__ __forceinline__ short8 ld16(const unsigned short* p) {
    return *reinterpret_cast<const short8*>(p);
}

// 8-load stage bundle: two 4-load groups (13-bit signed offset => max +4095)
#define LDBUNDLE(BASE) do { \
    const unsigned long long b0 = (BASE); \
    const unsigned long long b1 = b0 + 4096; \
    asm volatile( \
        "global_load_dwordx4 %0, %4, off sc0 sc1\n\t" \
        "global_load_dwordx4 %1, %4, off offset:1024 sc0 sc1\n\t" \
        "global_load_dwordx4 %2, %4, off offset:2048 sc0 sc1\n\t" \
        "global_load_dwordx4 %3, %4, off offset:3072 sc0 sc1" \
        : "=v"(v[0]), "=v"(v[1]), "=v"(v[2]), "=v"(v[3]) : "v"(b0) : "memory"); \
    asm volatile( \
        "global_load_dwordx4 %0, %4, off sc0 sc1\n\t" \
        "global_load_dwordx4 %1, %4, off offset:1024 sc0 sc1\n\t" \
        "global_load_dwordx4 %2, %4, off offset:2048 sc0 sc1\n\t" \
        "global_load_dwordx4 %3, %4, off offset:3072 sc0 sc1" \
        : "=v"(v[4]), "=v"(v[5]), "=v"(v[6]), "=v"(v[7]) : "v"(b1) : "memory"); \
} while (0)

// ---------------- zero-init h buffer 0 and flag block ----------------
__global__ void k_init(unsigned short* __restrict__ hb0, int* __restrict__ flags) {
    int i = blockIdx.x * 256 + threadIdx.x;
    if (i < BB * HH) hb0[i] = 0;
    if (i < 16384) flags[i] = 0;   // leaves (g,slot)*32, go at 8192+g*32
}

// ---------------- Wh -> bf16, transposed, gate-interleaved ----------------
__global__ void k_conv_wh(const float* __restrict__ Wfh, const float* __restrict__ Wih,
                          const float* __restrict__ Wgh, const float* __restrict__ Woh,
                          unsigned short* __restrict__ WhT) {
    __shared__ float t[32][33];
    int g = blockIdx.z;
    const float* W = (g == 0) ? Wfh : (g == 1) ? Wih : (g == 2) ? Wgh : Woh;
    int h0 = blockIdx.x * 32, k0 = blockIdx.y * 32;
    int tx = threadIdx.x & 31, ty = threadIdx.x >> 5;
    for (int r = 0; r < 4; r++) {
        int k = ty + r * 8;
        t[k][tx] = W[(size_t)(k0 + k) * HH + h0 + tx];
    }
    __syncthreads();
    for (int r = 0; r < 4; r++) {
        int hl = ty + r * 8;
        int j  = (h0 + hl) * 4 + g;
        WhT[(size_t)j * HH + k0 + tx] = f2b(t[tx][hl]);
    }
}

// ---------------- proj[c][j] = emb[c,:] @ Wx[:,hcol] + b ----------------
__global__ void k_proj(const float* __restrict__ emb,
                       const float* __restrict__ Wfx, const float* __restrict__ Wix,
                       const float* __restrict__ Wgx, const float* __restrict__ Wox,
                       const float* __restrict__ bf_, const float* __restrict__ bi_,
                       const float* __restrict__ bg_, const float* __restrict__ bo_,
                       float* __restrict__ proj) {
    int c = blockIdx.y;
    int j = blockIdx.x * 256 + threadIdx.x;
    int hcol = j >> 2, g = j & 3;
    const float* Wx = (g == 0) ? Wfx : (g == 1) ? Wix : (g == 2) ? Wgx : Wox;
    const float* bb = (g == 0) ? bf_ : (g == 1) ? bi_ : (g == 2) ? bg_ : bo_;
    float acc = bb[hcol];
    const float* er = emb + (size_t)c * DD;
    for (int d = 0; d < DD; d++) acc += er[d] * Wx[(size_t)d * HH + hcol];
    proj[(size_t)c * G4 + j] = acc;
}

// ---------------- persistent LSTM scan ----------------
// 8 groups x 16 rows. 128 WGs x 256 thr (4 waves). Block k = wg>>5 (32 WGs):
// phase A -> group 2k, phase B -> group 2k+1, same slot = wg&31, same
// gate-cols [slot*128, +128) both phases => one B-register set (256 regs).
// h slice (16 rows x 1024 k, fragment-major, 32 KB) staged once per WG into
// LDS; 4 waves share via ds_read (A volume 32 -> 8 MB/step). Stage bundle for
// the NEXT phase is prefetched right after this phase's MFMA; polls target
// flags posted >= 1 phase earlier, so propagation latency is hidden.
// All dynamic traffic (h, flags) via sc0 sc1 (L3 coherence point). Sync is
// intra-block only: 32 leaves + slot-0 aggregator + go word per group.
__global__ __launch_bounds__(256, 1)
void k_scan(const int* __restrict__ x, const float* __restrict__ proj,
            const unsigned short* __restrict__ WhT,
            unsigned short* __restrict__ hb0, unsigned short* __restrict__ hb1,
            float* __restrict__ hf32, int* __restrict__ flags) {
    const int wg = blockIdx.x, tid = threadIdx.x;
    const int lane = tid & 63, wv = tid >> 6;
    const int l15 = lane & 15, q4 = lane >> 4;
    const int blk = wg >> 5, slot = wg & 31;
    const int gA = blk * 2, gB = blk * 2 + 1;
    const int urow = tid & 15, hl = tid >> 4;        // pointwise: row, hcol-pair
    const int jg0 = slot * 128 + wv * 32 + l15;      // N-tile 0 gate-col (+16 = tile 1)
    const bool isAgg = (slot == 0) && (wv == 0);

    __shared__ unsigned short stage[16384];          // 32 KB h slice
    __shared__ float sg[16][132];                    // gates [row][WG-local col]
    __shared__ int   clsS[2][16];                    // [0]=phase-A cls, [1]=phase-B cls

    // ---- B fragments, full K, both N-tiles (256 regs) ----
    short8 breg0[32], breg1[32];
    {
        const unsigned short* B0 = WhT + (size_t)jg0 * HH + q4 * 8;
        const unsigned short* B1 = WhT + (size_t)(jg0 + 16) * HH + q4 * 8;
        #pragma unroll
        for (int kk = 0; kk < 32; kk++) {
            breg0[kk] = ld16(B0 + kk * 32);
            breg1[kk] = ld16(B1 + kk * 32);
        }
    }

    float CstA[2] = {0.0f, 0.0f}, CstB[2] = {0.0f, 0.0f};
    short8 v[8];   // prefetched stage bundle

    // ---- pre-loop: cls for A@0, stage bundle for A@0 (hb0 zeros) ----
    if (tid < 16) clsS[0][tid] = x[(size_t)(gA * 16 + tid) * SS];
    LDBUNDLE((unsigned long long)(hb0 + gA * 16384 + wv * 4096 + lane * 8));
    __syncthreads();

    // one phase of the interleaved scan
    auto phase = [&](int g, int gn, int epNext, unsigned short* hout,
                     const unsigned short* hinNext, float* Cst,
                     int par, int parN, int iN, bool pre, bool doPost, int i) {
        // 1) wait prefetched bundle (mostly flown during previous phase tail)
        asm volatile("s_waitcnt vmcnt(0)"
                     : "+v"(v[0]), "+v"(v[1]), "+v"(v[2]), "+v"(v[3]),
                       "+v"(v[4]), "+v"(v[5]), "+v"(v[6]), "+v"(v[7]) :: "memory");
        // 2) LDS stage
        #pragma unroll
        for (int k2 = 0; k2 < 8; k2++)
            *reinterpret_cast<short8*>(&stage[wv * 4096 + k2 * 512 + lane * 8]) = v[k2];
        __syncthreads();   // S2: stage ready

        // 3) proj gather + MFMA (ds_read from shared stage)
        float pr0[4], pr1[4];
        #pragma unroll
        for (int r = 0; r < 4; r++) {
            int cc = clsS[par][q4 * 4 + r];
            pr0[r] = proj[(size_t)cc * G4 + jg0];
            pr1[r] = proj[(size_t)cc * G4 + jg0 + 16];
        }
        f32x4 acc0 = {0.f, 0.f, 0.f, 0.f}, acc1 = {0.f, 0.f, 0.f, 0.f};
        #pragma unroll
        for (int kk = 0; kk < 32; kk++) {
            short8 a = *reinterpret_cast<const short8*>(&stage[kk * 512 + lane * 8]);
            acc0 = __builtin_amdgcn_mfma_f32_16x16x32_bf16(a, breg0[kk], acc0, 0, 0, 0);
            acc1 = __builtin_amdgcn_mfma_f32_16x16x32_bf16(a, breg1[kk], acc1, 0, 0, 0);
        }

        // 4) poll next phase's group + prefetch its stage bundle
        if (pre) {
            if (isAgg) {
                const unsigned long long la =
                    (unsigned long long)(flags + ((size_t)(gn * 32 + (lane & 31)) * 32));
                int got;
                do {
                    asm volatile("global_load_dword %0, %1, off sc0 sc1\n\t"
                                 "s_waitcnt vmcnt(0)"
                                 : "=v"(got) : "v"(la) : "memory");
                } while (__ballot(got >= epNext) != ~0ull);
                if (tid == 0) {
                    const unsigned long long ga =
                        (unsigned long long)(flags + (8192 + gn * 32));
                    asm volatile("global_store_dword %0, %1, off sc0 sc1"
                                 :: "v"(ga), "v"(epNext) : "memory");
                }
            } else {
                const unsigned long long ga =
                    (unsigned long long)(flags + (8192 + gn * 32));
                int got;
                do {
                    asm volatile("global_load_dword %0, %1, off sc0 sc1\n\t"
                                 "s_waitcnt vmcnt(0)"
                                 : "=v"(got) : "v"(ga) : "memory");
                } while (got < epNext);
            }
            LDBUNDLE((unsigned long long)(hinNext + gn * 16384 + wv * 4096 + lane * 8));
        }

        // 5) epilogue: sigmoid(acc + proj) -> sg
        // C/D 16x16 (m89/m91): col = lane&15, row = (lane>>4)*4 + reg
        #pragma unroll
        for (int r = 0; r < 4; r++) {
            int row = q4 * 4 + r;
            sg[row][wv * 32 + l15]      = sigm(acc0[r] + pr0[r]);
            sg[row][wv * 32 + 16 + l15] = sigm(acc1[r] + pr1[r]);
        }
        __syncthreads();   // S3

        // 6) pointwise: thread (urow, 2 hcols); also prefetch next phase's cls
        {
            const float rr = (clsS[par][urow] > 0) ? 1.0f : 0.0f;
            unsigned short hv[2];
            #pragma unroll
            for (int q = 0; q < 2; q++) {
                float4 gq = *reinterpret_cast<const float4*>(&sg[urow][hl * 8 + q * 4]);
                float cn = (gq.z * gq.y + Cst[q] * gq.x) * rr;   // (g*i + C*f)*r
                Cst[q] = cn;
                float hvv = gq.w * tanh_(cn);
                hv[q] = f2b(hvv);
                if (i == SS - 1)
                    hf32[(size_t)(g * 16 + urow) * HH + slot * 32 + hl * 2 + q] = hvv;
            }
            unsigned int pk = (unsigned int)hv[0] | ((unsigned int)hv[1] << 16);
            const unsigned long long sw = (unsigned long long)(hout + g * 16384
                + slot * 512 + ((hl >> 2) * 16 + urow) * 8 + (hl & 3) * 2);
            asm volatile("global_store_dword %0, %1, off sc0 sc1"
                         :: "v"(sw), "v"(pk) : "memory");
            if (pre && tid < 16)
                clsS[parN][tid] = x[(size_t)(gn * 16 + tid) * SS + iN];
        }

        // 7) drain h-store (bundle residual rides along), then post leaf
        asm volatile("s_waitcnt vmcnt(0)" ::: "memory");
        __syncthreads();   // S4
        if (doPost && tid == 0) {
            const unsigned long long pa =
                (unsigned long long)(flags + ((size_t)(g * 32 + slot) * 32));
            int e = i + 1;
            asm volatile("global_store_dword %0, %1, off sc0 sc1"
                         :: "v"(pa), "v"(e) : "memory");
        }
    };

    for (int i = 0; i < SS; i++) {
        const unsigned short* hin  = (i & 1) ? hb1 : hb0;   // epoch-i h
        unsigned short*       hout = (i & 1) ? hb0 : hb1;   // epoch-(i+1) h
        const bool last = (i == SS - 1);
        // phase A: group gA step i; next = gB@i (reads hin)
        phase(gA, gB, i, hout, hin, CstA, 0, 1, i, true, !last, i);
        // phase B: group gB step i; next = gA@(i+1) (reads hout)
        phase(gB, gA, i + 1, hout, hout, CstB, 1, 0, i + 1, !last, !last, i);
    }
}

// ---------------- final projection + log_softmax ----------------
__global__ void k_final(const float* __restrict__ hf32, const float* __restrict__ Wph,
                        const float* __restrict__ bp, float* __restrict__ out) {
    __shared__ float red[128];
    int b = blockIdx.x, c = threadIdx.x;
    const float* hr = hf32 + (size_t)b * HH;
    float acc = bp[c];
    for (int k = 0; k < HH; k++) acc += hr[k] * Wph[(size_t)k * NCC + c];
    red[c] = acc;
    __syncthreads();
    for (int st = 64; st > 0; st >>= 1) {
        if (c < st) red[c] = fmaxf(red[c], red[c + st]);
        __syncthreads();
    }
    float m = red[0];
    __syncthreads();
    red[c] = __expf(acc - m);
    __syncthreads();
    for (int st = 64; st > 0; st >>= 1) {
        if (c < st) red[c] += red[c + st];
        __syncthreads();
    }
    out[(size_t)b * NCC + c] = acc - m - __logf(red[0]);
}

extern "C" void kernel_launch(void* const* d_in, const int* in_sizes, int n_in,
                              void* d_out, int out_size, void* d_ws, size_t ws_size,
                              hipStream_t stream) {
    const int*   x   = (const int*)  d_in[0];
    const float* emb = (const float*)d_in[1];
    const float* Wfx = (const float*)d_in[2];
    const float* Wfh = (const float*)d_in[3];
    const float* bf_ = (const float*)d_in[4];
    const float* Wix = (const float*)d_in[5];
    const float* Wih = (const float*)d_in[6];
    const float* bi_ = (const float*)d_in[7];
    const float* Wgx = (const float*)d_in[8];
    const float* Wgh = (const float*)d_in[9];
    const float* bg_ = (const float*)d_in[10];
    const float* Wox = (const float*)d_in[11];
    const float* Woh = (const float*)d_in[12];
    const float* bo_ = (const float*)d_in[13];
    const float* Wph = (const float*)d_in[14];
    const float* bp_ = (const float*)d_in[15];
    float* out = (float*)d_out;

    char* ws = (char*)d_ws;
    unsigned short* WhT   = (unsigned short*)(ws);              // 8 MB
    float*          proj  = (float*)(ws + 8388608);             // 2.02 MB
    int*            flags = (int*)(ws + 10502656);              // 64 KB
    unsigned short* hb0   = (unsigned short*)(ws + 10568192);   // 256 KB
    unsigned short* hb1   = (unsigned short*)(ws + 10830336);   // 256 KB
    float*          hf32  = (float*)(ws + 11092480);            // 512 KB

    k_init<<<dim3(512), dim3(256), 0, stream>>>(hb0, flags);
    k_conv_wh<<<dim3(32, 32, 4), dim3(256), 0, stream>>>(Wfh, Wih, Wgh, Woh, WhT);
    k_proj<<<dim3(16, NCLS), dim3(256), 0, stream>>>(emb, Wfx, Wix, Wgx, Wox,
                                                     bf_, bi_, bg_, bo_, proj);
    k_scan<<<dim3(NWG), dim3(256), 0, stream>>>(x, proj, WhT, hb0, hb1, hf32, flags);
    k_final<<<dim3(128), dim3(128), 0, stream>>>(hf32, Wph, bp_, out);
}